// Round 14
// baseline (1171.671 us; speedup 1.0000x reference)
//
#include <hip/hip_runtime.h>
#include <hip/hip_bf16.h>

namespace {

constexpr int D_      = 1024;
constexpr int THREE_D = 3072;
constexpr int B_      = 8;
constexpr int M_      = 16384;   // B*L tokens

typedef unsigned short u16;
typedef __attribute__((ext_vector_type(8))) short bf16x8;
typedef __attribute__((ext_vector_type(4))) float f32x4;

__device__ __forceinline__ u16 f2bf(float f) {
  unsigned u = __float_as_uint(f);
  u += 0x7fffu + ((u >> 16) & 1u);   // round-to-nearest-even
  return (u16)(u >> 16);
}

// tanh-form gelu via native v_exp_f32; |err| <= ~3e-3 vs erf-gelu.
__device__ __forceinline__ float gelu_fast(float x) {
  float u = 0.7978845608028654f * (x + 0.044715f * x * x * x);
  float e = __expf(2.0f * u);
  float th = 1.0f - 2.0f * __builtin_amdgcn_rcpf(e + 1.0f);
  return 0.5f * x * (1.0f + th);
}

// ---------- weight transpose + f32->bf16 pack ----------
__global__ void packT(const float* __restrict__ s0, const float* __restrict__ s1,
                      u16* __restrict__ dst, int K, int N, int mode) {
  __shared__ float tile[32][33];
  int n0 = blockIdx.x * 32, k0 = blockIdx.y * 32;
  int tx = threadIdx.x, ty = threadIdx.y;
  for (int i = ty; i < 32; i += 8) {
    int k = k0 + i, n = n0 + tx;
    float v;
    if (mode == 1)      { int h = N >> 1; v = (n < h) ? s0[(size_t)k * h + n] : s1[(size_t)k * h + (n - h)]; }
    else if (mode == 2) { int h = K >> 1; v = (k < h) ? s0[(size_t)k * N + n] : s1[(size_t)(k - h) * N + n]; }
    else                v = s0[(size_t)k * N + n];
    tile[i][tx] = v;
  }
  __syncthreads();
  for (int i = ty; i < 32; i += 8) {
    int n = n0 + i, k = k0 + tx;
    dst[(size_t)n * K + k] = f2bf(tile[tx][i]);
  }
}

// ---------- ada embedding, K-split ----------
__global__ __launch_bounds__(256) void ada_part(const float* __restrict__ t,
                                                const float* __restrict__ W,
                                                float* __restrict__ part) {
  __shared__ float s[B_ * 256];
  const int jb = blockIdx.x, kc = blockIdx.y;
  const int tid = threadIdx.x;
  const int k0 = kc * 256;
  for (int idx = tid; idx < B_ * 256; idx += 256) {
    float v = t[((idx >> 8) << 10) + k0 + (idx & 255)];
    s[idx] = v / (1.0f + expf(-v));
  }
  __syncthreads();
  const int j = jb * 256 + tid;
  float acc[B_];
#pragma unroll
  for (int b = 0; b < B_; ++b) acc[b] = 0.f;
  for (int k = 0; k < 256; ++k) {
    const float w = W[(size_t)(k0 + k) * THREE_D + j];
#pragma unroll
    for (int b = 0; b < B_; ++b) acc[b] = fmaf(s[(b << 8) + k], w, acc[b]);
  }
#pragma unroll
  for (int b = 0; b < B_; ++b)
    part[((size_t)kc * B_ + b) * THREE_D + j] = acc[b];
}

__global__ __launch_bounds__(256) void ada_reduce(const float* __restrict__ part,
                                                  const float* __restrict__ bias,
                                                  float* __restrict__ out) {
  const int j = blockIdx.x * 256 + threadIdx.x;
  const int b = blockIdx.y;
  float v = bias[j];
#pragma unroll
  for (int kc = 0; kc < 4; ++kc) v += part[((size_t)kc * B_ + b) * THREE_D + j];
  out[(size_t)b * THREE_D + j] = v;
}

// ---------- LayerNorm + adaLN modulate -> bf16 ----------
__global__ __launch_bounds__(256) void ln_mod(const float* __restrict__ in,
                                              const float* __restrict__ modv,
                                              u16* __restrict__ out) {
  const int row = blockIdx.x;
  const int b = row >> 11;  // L = 2048
  const int tid = threadIdx.x;
  const float4 v = *(const float4*)(in + (size_t)row * D_ + tid * 4);
  float s = v.x + v.y + v.z + v.w;
  float q = v.x * v.x + v.y * v.y + v.z * v.z + v.w * v.w;
#pragma unroll
  for (int off = 32; off > 0; off >>= 1) {
    s += __shfl_down(s, off);
    q += __shfl_down(q, off);
  }
  __shared__ float red[8];
  const int wave = tid >> 6, lane = tid & 63;
  if (lane == 0) { red[wave] = s; red[4 + wave] = q; }
  __syncthreads();
  float ts = red[0] + red[1] + red[2] + red[3];
  float tq = red[4] + red[5] + red[6] + red[7];
  const float mu = ts * (1.0f / D_);
  const float var = tq * (1.0f / D_) - mu * mu;
  const float rstd = rsqrtf(var + 1e-6f);
  const float4 sh = *(const float4*)(modv + (size_t)b * THREE_D + tid * 4);
  const float4 sc = *(const float4*)(modv + (size_t)b * THREE_D + D_ + tid * 4);
  float o0 = (v.x - mu) * rstd * (1.0f + sc.x) + sh.x;
  float o1 = (v.y - mu) * rstd * (1.0f + sc.y) + sh.y;
  float o2 = (v.z - mu) * rstd * (1.0f + sc.z) + sh.z;
  float o3 = (v.w - mu) * rstd * (1.0f + sc.w) + sh.w;
  uint2 pk;
  pk.x = (unsigned)f2bf(o0) | ((unsigned)f2bf(o1) << 16);
  pk.y = (unsigned)f2bf(o2) | ((unsigned)f2bf(o3) << 16);
  *(uint2*)(out + (size_t)row * D_ + tid * 4) = pk;
}

// ---------- bf16 MFMA GEMM: 128x128, 4 waves, NO-LDS register-fragment -----
// Round-14 theory: r13's counters reconcile as LDS-bandwidth-bound (per
// CU-tile-slot: LDS pipe ~2000 cyc vs MFMA 1240 vs measured 2290). B (4 MB)
// and A (32 MB) are L2/L3-resident -> staging through LDS is pure overhead
// (Common-mistake #7). Here each wave loads MFMA fragments DIRECTLY
// global->VGPR: per lane 16B; 4 lanes/row -> 64B contiguous segments/row,
// 16 rows per instruction (L2-served). Zero LDS, zero barriers, no
// gload_lds; ~164 unified VGPR -> 3 blocks/CU; cross-wave TLP (m114) hides
// L2 latency; no-sync loop lets the compiler pipeline loads across t.
// Fragment mapping (ref-verified in rounds 1-13): for 16x16x32 MFMA, lane
// (l15,l4) holds A[row=l15][k=l4*8..+8] -> addr = row*K + s*32 + l4*8.
constexpr int BM = 128, BN = 128, BK = 64;

template <int EPI, int NN, int KK>
__global__ __launch_bounds__(256)
void gemm_rf(const u16* __restrict__ A, const u16* __restrict__ Bt,
             const float* __restrict__ b0, const float* __restrict__ b1,
             const float* __restrict__ xres, const int* __restrict__ mask,
             const float* __restrict__ gate,
             float* __restrict__ outf, u16* __restrict__ outh) {
  const int tid = threadIdx.x;
  const int wave = tid >> 6, lane = tid & 63;
  const int wr = wave >> 1, wc = wave & 1;
  const int l15 = lane & 15, l4 = lane >> 4;

  constexpr int LGX = (NN == 2048) ? 4 : 3;
  const int nwg = gridDim.x;
  const int flat = blockIdx.x;
  const int swz = (flat & 7) * (nwg >> 3) + (flat >> 3);
  const int bx = swz & ((1 << LGX) - 1), by = swz >> LGX;
  const int m0 = by * BM, n0 = bx * BN;

  // per-lane fragment base pointers: 4 A-rows + 4 B-rows, advanced += BK
  const u16* pa0 = A  + (size_t)(m0 + wr * 64 +  0 + l15) * KK + l4 * 8;
  const u16* pa1 = A  + (size_t)(m0 + wr * 64 + 16 + l15) * KK + l4 * 8;
  const u16* pa2 = A  + (size_t)(m0 + wr * 64 + 32 + l15) * KK + l4 * 8;
  const u16* pa3 = A  + (size_t)(m0 + wr * 64 + 48 + l15) * KK + l4 * 8;
  const u16* pb0 = Bt + (size_t)(n0 + wc * 64 +  0 + l15) * KK + l4 * 8;
  const u16* pb1 = Bt + (size_t)(n0 + wc * 64 + 16 + l15) * KK + l4 * 8;
  const u16* pb2 = Bt + (size_t)(n0 + wc * 64 + 32 + l15) * KK + l4 * 8;
  const u16* pb3 = Bt + (size_t)(n0 + wc * 64 + 48 + l15) * KK + l4 * 8;

  f32x4 acc[4][4];
#pragma unroll
  for (int i = 0; i < 4; ++i)
#pragma unroll
    for (int j = 0; j < 4; ++j) acc[i][j] = (f32x4){0.f, 0.f, 0.f, 0.f};

  constexpr int NT = KK / BK;
  for (int t = 0; t < NT; ++t) {
    bf16x8 af[4][2], bf[4][2];
#pragma unroll
    for (int s = 0; s < 2; ++s) {
      af[0][s] = *(const bf16x8*)(pa0 + s * 32);
      af[1][s] = *(const bf16x8*)(pa1 + s * 32);
      af[2][s] = *(const bf16x8*)(pa2 + s * 32);
      af[3][s] = *(const bf16x8*)(pa3 + s * 32);
      bf[0][s] = *(const bf16x8*)(pb0 + s * 32);
      bf[1][s] = *(const bf16x8*)(pb1 + s * 32);
      bf[2][s] = *(const bf16x8*)(pb2 + s * 32);
      bf[3][s] = *(const bf16x8*)(pb3 + s * 32);
    }
#pragma unroll
    for (int i = 0; i < 4; ++i)
#pragma unroll
      for (int j = 0; j < 4; ++j)
#pragma unroll
        for (int s = 0; s < 2; ++s)
          acc[i][j] = __builtin_amdgcn_mfma_f32_16x16x32_bf16(af[i][s], bf[j][s], acc[i][j], 0, 0, 0);
    pa0 += BK; pa1 += BK; pa2 += BK; pa3 += BK;
    pb0 += BK; pb1 += BK; pb2 += BK; pb3 += BK;
  }

#pragma unroll
  for (int i = 0; i < 4; ++i) {
#pragma unroll
    for (int r = 0; r < 4; ++r) {
      const int m = m0 + wr * 64 + i * 16 + l4 * 4 + r;
#pragma unroll
      for (int j = 0; j < 4; ++j) {
        const int n = n0 + wc * 64 + j * 16 + l15;
        float v = acc[i][j][r];
        if constexpr (EPI == 0 || EPI == 1) {
          v += (n < (NN >> 1)) ? b0[n] : b1[n - (NN >> 1)];
          outh[(size_t)m * NN + n] = f2bf(gelu_fast(v));
        } else if constexpr (EPI == 2) {
          v += b0[n] + b1[n];
          float res = xres[(size_t)m * NN + n];
          if (mask[m] != 0) res += gate[(size_t)(m >> 11) * THREE_D + n] * v;
          outf[(size_t)m * NN + n] = res;
        } else {
          v += b0[n];
          outf[(size_t)m * NN + n] = outf[(size_t)m * NN + n] +
                                     gate[(size_t)(m >> 11) * THREE_D + n] * v;
        }
      }
    }
  }
}

}  // namespace

extern "C" void kernel_launch(void* const* d_in, const int* in_sizes, int n_in,
                              void* d_out, int out_size, void* d_ws, size_t ws_size,
                              hipStream_t stream) {
  const float* x       = (const float*)d_in[0];
  const float* t       = (const float*)d_in[1];
  const int*   mask    = (const int*)d_in[2];
  const float* ada_w   = (const float*)d_in[3];
  const float* ada_b   = (const float*)d_in[4];
  const float* ssm_w1  = (const float*)d_in[5];
  const float* ssm_b1  = (const float*)d_in[6];
  const float* ssm_w2  = (const float*)d_in[7];
  const float* ssm_b2  = (const float*)d_in[8];
  const float* bwd_w1  = (const float*)d_in[9];
  const float* bwd_b1  = (const float*)d_in[10];
  const float* bwd_w2  = (const float*)d_in[11];
  const float* bwd_b2  = (const float*)d_in[12];
  const float* ffada_w = (const float*)d_in[13];
  const float* ffada_b = (const float*)d_in[14];
  const float* ff_w1   = (const float*)d_in[15];
  const float* ff_b1   = (const float*)d_in[16];
  const float* ff_w2   = (const float*)d_in[17];
  const float* ff_b2   = (const float*)d_in[18];
  float* out = (float*)d_out;

  char* ws = (char*)d_ws;
  u16* normb = (u16*)ws;                                        // 16384*1024 bf16 (32 MB)
  u16* Hb    = (u16*)(ws + (size_t)M_ * D_ * 2);                // 16384*2048 bf16 (64 MB)
  u16* w1t   = (u16*)(ws + (size_t)M_ * D_ * 2 + (size_t)M_ * 2 * D_ * 2);
  u16* w2t   = w1t + (size_t)2 * D_ * D_;
  u16* fw1t  = w2t + (size_t)2 * D_ * D_;
  u16* fw2t  = fw1t + (size_t)2 * D_ * D_;
  float* emb   = (float*)(fw2t + (size_t)2 * D_ * D_);          // [8][3072]
  float* ffada = emb + B_ * THREE_D;                            // [8][3072]
  float* part0 = (float*)Hb;                                    // [4][8][3072]
  float* part1 = part0 + 4 * B_ * THREE_D;

  dim3 tb(32, 8);
  packT<<<dim3(64, 32), tb, 0, stream>>>(ssm_w1, bwd_w1, w1t, D_, 2 * D_, 1);
  packT<<<dim3(32, 64), tb, 0, stream>>>(ssm_w2, bwd_w2, w2t, 2 * D_, D_, 2);
  packT<<<dim3(64, 32), tb, 0, stream>>>(ff_w1, nullptr, fw1t, D_, 2 * D_, 0);
  packT<<<dim3(32, 64), tb, 0, stream>>>(ff_w2, nullptr, fw2t, 2 * D_, D_, 0);

  ada_part<<<dim3(12, 4), 256, 0, stream>>>(t, ada_w, part0);
  ada_part<<<dim3(12, 4), 256, 0, stream>>>(t, ffada_w, part1);
  ada_reduce<<<dim3(12, 8), 256, 0, stream>>>(part0, ada_b, emb);
  ada_reduce<<<dim3(12, 8), 256, 0, stream>>>(part1, ffada_b, ffada);

  ln_mod<<<M_, 256, 0, stream>>>(x, emb, normb);

  // H = gelu(norm @ W1cat + b1cat)                [16384 x 2048]
  gemm_rf<0, 2048, 1024><<<2048, 256, 0, stream>>>(normb, w1t,
                                                   ssm_b1, bwd_b1, nullptr, nullptr, nullptr,
                                                   nullptr, Hb);
  // x_mid = x + mask*gate_msa*(H @ W2cat + b2sum) -> d_out
  gemm_rf<2, 1024, 2048><<<1024, 256, 0, stream>>>(Hb, w2t,
                                                   ssm_b2, bwd_b2, x, mask, emb + 2 * D_,
                                                   out, nullptr);
  ln_mod<<<M_, 256, 0, stream>>>(out, ffada, normb);

  // H = gelu(ff_norm @ ff_w1 + ff_b1)             [16384 x 2048]
  gemm_rf<1, 2048, 1024><<<2048, 256, 0, stream>>>(normb, fw1t,
                                                   ff_b1, ff_b1 + D_, nullptr, nullptr, nullptr,
                                                   nullptr, Hb);
  // out = x_mid + gate_mlp*(H @ ff_w2 + ff_b2)    (in-place on d_out)
  gemm_rf<3, 1024, 2048><<<1024, 256, 0, stream>>>(Hb, fw2t,
                                                   ff_b2, nullptr, nullptr, nullptr, ffada + 2 * D_,
                                                   out, nullptr);
}

// Round 15
// 487.435 us; speedup vs baseline: 2.4037x; 2.4037x over previous
//
#include <hip/hip_runtime.h>
#include <hip/hip_bf16.h>

namespace {

constexpr int D_      = 1024;
constexpr int THREE_D = 3072;
constexpr int B_      = 8;
constexpr int M_      = 16384;   // B*L tokens

typedef unsigned short u16;
typedef __attribute__((ext_vector_type(8))) short bf16x8;
typedef __attribute__((ext_vector_type(4))) float f32x4;

__device__ __forceinline__ u16 f2bf(float f) {
  unsigned u = __float_as_uint(f);
  u += 0x7fffu + ((u >> 16) & 1u);   // round-to-nearest-even
  return (u16)(u >> 16);
}

// tanh-form gelu via native v_exp_f32; |err| <= ~3e-3 vs erf-gelu.
__device__ __forceinline__ float gelu_fast(float x) {
  float u = 0.7978845608028654f * (x + 0.044715f * x * x * x);
  float e = __expf(2.0f * u);
  float th = 1.0f - 2.0f * __builtin_amdgcn_rcpf(e + 1.0f);
  return 0.5f * x * (1.0f + th);
}

// direct global->LDS 16B async copy. LDS dest is wave-uniform base + lane*16.
typedef __attribute__((address_space(3))) unsigned int   lds_uint;
typedef const __attribute__((address_space(1))) unsigned int gl_uint;
__device__ __forceinline__ void gload16(const void* g, void* l) {
  __builtin_amdgcn_global_load_lds((gl_uint*)g, (lds_uint*)l, 16, 0, 0);
}

// ROUND-15 KEY: inline-asm ds_read_b128. Plain C++ LDS reads after issuing
// global_load_lds get a compiler-inserted s_waitcnt vmcnt(0) (alias safety:
// gload_lds WRITES LDS), which silently drained the pipeline in rounds 5-13
// and made every schedule variant identical. Asm reads are opaque to the
// waitcnt pass; we supply our own lgkmcnt(0)+sched_barrier(0) (rule #18).
typedef __attribute__((address_space(3))) const u16 lds_cu16;
__device__ __forceinline__ bf16x8 ds_read128(const u16* p) {
  bf16x8 r;
  asm volatile("ds_read_b128 %0, %1" : "=v"(r) : "v"((lds_cu16*)p));
  return r;
}

// ---------- weight transpose + f32->bf16 pack ----------
__global__ void packT(const float* __restrict__ s0, const float* __restrict__ s1,
                      u16* __restrict__ dst, int K, int N, int mode) {
  __shared__ float tile[32][33];
  int n0 = blockIdx.x * 32, k0 = blockIdx.y * 32;
  int tx = threadIdx.x, ty = threadIdx.y;
  for (int i = ty; i < 32; i += 8) {
    int k = k0 + i, n = n0 + tx;
    float v;
    if (mode == 1)      { int h = N >> 1; v = (n < h) ? s0[(size_t)k * h + n] : s1[(size_t)k * h + (n - h)]; }
    else if (mode == 2) { int h = K >> 1; v = (k < h) ? s0[(size_t)k * N + n] : s1[(size_t)(k - h) * N + n]; }
    else                v = s0[(size_t)k * N + n];
    tile[i][tx] = v;
  }
  __syncthreads();
  for (int i = ty; i < 32; i += 8) {
    int n = n0 + i, k = k0 + tx;
    dst[(size_t)n * K + k] = f2bf(tile[tx][i]);
  }
}

// ---------- ada embedding, K-split ----------
__global__ __launch_bounds__(256) void ada_part(const float* __restrict__ t,
                                                const float* __restrict__ W,
                                                float* __restrict__ part) {
  __shared__ float s[B_ * 256];
  const int jb = blockIdx.x, kc = blockIdx.y;
  const int tid = threadIdx.x;
  const int k0 = kc * 256;
  for (int idx = tid; idx < B_ * 256; idx += 256) {
    float v = t[((idx >> 8) << 10) + k0 + (idx & 255)];
    s[idx] = v / (1.0f + expf(-v));
  }
  __syncthreads();
  const int j = jb * 256 + tid;
  float acc[B_];
#pragma unroll
  for (int b = 0; b < B_; ++b) acc[b] = 0.f;
  for (int k = 0; k < 256; ++k) {
    const float w = W[(size_t)(k0 + k) * THREE_D + j];
#pragma unroll
    for (int b = 0; b < B_; ++b) acc[b] = fmaf(s[(b << 8) + k], w, acc[b]);
  }
#pragma unroll
  for (int b = 0; b < B_; ++b)
    part[((size_t)kc * B_ + b) * THREE_D + j] = acc[b];
}

__global__ __launch_bounds__(256) void ada_reduce(const float* __restrict__ part,
                                                  const float* __restrict__ bias,
                                                  float* __restrict__ out) {
  const int j = blockIdx.x * 256 + threadIdx.x;
  const int b = blockIdx.y;
  float v = bias[j];
#pragma unroll
  for (int kc = 0; kc < 4; ++kc) v += part[((size_t)kc * B_ + b) * THREE_D + j];
  out[(size_t)b * THREE_D + j] = v;
}

// ---------- LayerNorm + adaLN modulate -> bf16 ----------
__global__ __launch_bounds__(256) void ln_mod(const float* __restrict__ in,
                                              const float* __restrict__ modv,
                                              u16* __restrict__ out) {
  const int row = blockIdx.x;
  const int b = row >> 11;  // L = 2048
  const int tid = threadIdx.x;
  const float4 v = *(const float4*)(in + (size_t)row * D_ + tid * 4);
  float s = v.x + v.y + v.z + v.w;
  float q = v.x * v.x + v.y * v.y + v.z * v.z + v.w * v.w;
#pragma unroll
  for (int off = 32; off > 0; off >>= 1) {
    s += __shfl_down(s, off);
    q += __shfl_down(q, off);
  }
  __shared__ float red[8];
  const int wave = tid >> 6, lane = tid & 63;
  if (lane == 0) { red[wave] = s; red[4 + wave] = q; }
  __syncthreads();
  float ts = red[0] + red[1] + red[2] + red[3];
  float tq = red[4] + red[5] + red[6] + red[7];
  const float mu = ts * (1.0f / D_);
  const float var = tq * (1.0f / D_) - mu * mu;
  const float rstd = rsqrtf(var + 1e-6f);
  const float4 sh = *(const float4*)(modv + (size_t)b * THREE_D + tid * 4);
  const float4 sc = *(const float4*)(modv + (size_t)b * THREE_D + D_ + tid * 4);
  float o0 = (v.x - mu) * rstd * (1.0f + sc.x) + sh.x;
  float o1 = (v.y - mu) * rstd * (1.0f + sc.y) + sh.y;
  float o2 = (v.z - mu) * rstd * (1.0f + sc.z) + sh.z;
  float o3 = (v.w - mu) * rstd * (1.0f + sc.w) + sh.w;
  uint2 pk;
  pk.x = (unsigned)f2bf(o0) | ((unsigned)f2bf(o1) << 16);
  pk.y = (unsigned)f2bf(o2) | ((unsigned)f2bf(o3) << 16);
  *(uint2*)(out + (size_t)row * D_ + tid * 4) = pk;
}

// ---------- bf16 MFMA GEMM: 128x128, 4 waves, dbuf + asm-ds_read pipeline --
// r13 structure + double-buffered LDS (2x32KB -> still 2 blocks/CU) + asm
// fragment reads. Per tile: issue 8 gloads (t+1 -> buf^1) -> 16 asm ds_reads
// (no implicit vmcnt drain!) -> lgkmcnt(0)+sched_barrier -> 32 MFMA ->
// __syncthreads (compiler drain vmcnt(0) lands HERE, a full tile after
// issue -> residual wait ~0; also WAR fence for buffer recycle).
constexpr int BM = 128, BN = 128, BK = 64;

template <int EPI, int NN, int KK>
__global__ __launch_bounds__(256)
void gemm_bt(const u16* __restrict__ A, const u16* __restrict__ Bt,
             const float* __restrict__ b0, const float* __restrict__ b1,
             const float* __restrict__ xres, const int* __restrict__ mask,
             const float* __restrict__ gate,
             float* __restrict__ outf, u16* __restrict__ outh) {
  __shared__ u16 As[2][BM * BK];
  __shared__ u16 Bs[2][BN * BK];
  const int tid = threadIdx.x;
  const int wave = tid >> 6, lane = tid & 63;
  const int wr = wave >> 1, wc = wave & 1;
  const int l15 = lane & 15, l4 = lane >> 4;

  constexpr int LGX = (NN == 2048) ? 4 : 3;
  const int nwg = gridDim.x;
  const int flat = blockIdx.x;
  const int swz = (flat & 7) * (nwg >> 3) + (flat >> 3);
  const int bx = swz & ((1 << LGX) - 1), by = swz >> LGX;
  const int m0 = by * BM, n0 = bx * BN;

  // staging: wave w owns rows [w*32, w*32+32), 4 calls x 8 rows per matrix.
  // XOR slot permutation on the GLOBAL side (rule #21, 0 conflicts verified).
  const int sg = (lane & 7) ^ (lane >> 3);
  const u16* ga = A  + (size_t)(m0 + wave * 32 + (lane >> 3)) * KK + sg * 8;
  const u16* gb = Bt + (size_t)(n0 + wave * 32 + (lane >> 3)) * KK + sg * 8;
  const int ldso = wave * 32 * BK;          // wave-uniform linear dest

  // loop-invariant swizzled read offsets
  const int swz0 = ((l4 ^ (l15 & 7)) << 3);            // ks=0 slots
  const int swz1 = (((4 + l4) ^ (l15 & 7)) << 3);      // ks=1 slots
  const int arow = (wr * 64 + l15) * BK;
  const int brow = (wc * 64 + l15) * BK;

  f32x4 acc[4][4];
#pragma unroll
  for (int i = 0; i < 4; ++i)
#pragma unroll
    for (int j = 0; j < 4; ++j) acc[i][j] = (f32x4){0.f, 0.f, 0.f, 0.f};

  constexpr int NT = KK / BK;

  // prologue: stage tile 0 into buf 0
#pragma unroll
  for (int it = 0; it < 4; ++it) {
    gload16(ga + (size_t)(it * 8) * KK, As[0] + ldso + it * 8 * BK);
    gload16(gb + (size_t)(it * 8) * KK, Bs[0] + ldso + it * 8 * BK);
  }
  __syncthreads();

  for (int t = 0; t < NT; ++t) {
    const u16* as = As[t & 1];
    const u16* bs = Bs[t & 1];
    if (t + 1 < NT) {
      ga += BK; gb += BK;
      u16* An = As[(t + 1) & 1];
      u16* Bn = Bs[(t + 1) & 1];
#pragma unroll
      for (int it = 0; it < 4; ++it) {
        gload16(ga + (size_t)(it * 8) * KK, An + ldso + it * 8 * BK);
        gload16(gb + (size_t)(it * 8) * KK, Bn + ldso + it * 8 * BK);
      }
    }

    // asm fragment reads — no compiler-inserted vmcnt drain
    bf16x8 af[4][2], bf[4][2];
#pragma unroll
    for (int i = 0; i < 4; ++i) {
      af[i][0] = ds_read128(as + arow + i * 16 * BK + swz0);
      af[i][1] = ds_read128(as + arow + i * 16 * BK + swz1);
    }
#pragma unroll
    for (int j = 0; j < 4; ++j) {
      bf[j][0] = ds_read128(bs + brow + j * 16 * BK + swz0);
      bf[j][1] = ds_read128(bs + brow + j * 16 * BK + swz1);
    }
    asm volatile("s_waitcnt lgkmcnt(0)" ::: "memory");
    __builtin_amdgcn_sched_barrier(0);   // rule #18: pin MFMA after the wait

    __builtin_amdgcn_s_setprio(1);
#pragma unroll
    for (int i = 0; i < 4; ++i)
#pragma unroll
      for (int j = 0; j < 4; ++j)
#pragma unroll
        for (int s = 0; s < 2; ++s)
          acc[i][j] = __builtin_amdgcn_mfma_f32_16x16x32_bf16(af[i][s], bf[j][s], acc[i][j], 0, 0, 0);
    __builtin_amdgcn_s_setprio(0);

    // compiler attaches vmcnt(0) lgkmcnt(0) here — full-tile distance from
    // the gload issues, so residual wait ~0. Also the WAR fence.
    __syncthreads();
  }

#pragma unroll
  for (int i = 0; i < 4; ++i) {
#pragma unroll
    for (int r = 0; r < 4; ++r) {
      const int m = m0 + wr * 64 + i * 16 + l4 * 4 + r;
#pragma unroll
      for (int j = 0; j < 4; ++j) {
        const int n = n0 + wc * 64 + j * 16 + l15;
        float v = acc[i][j][r];
        if constexpr (EPI == 0 || EPI == 1) {
          v += (n < (NN >> 1)) ? b0[n] : b1[n - (NN >> 1)];
          outh[(size_t)m * NN + n] = f2bf(gelu_fast(v));
        } else if constexpr (EPI == 2) {
          v += b0[n] + b1[n];
          float res = xres[(size_t)m * NN + n];
          if (mask[m] != 0) res += gate[(size_t)(m >> 11) * THREE_D + n] * v;
          outf[(size_t)m * NN + n] = res;
        } else {
          v += b0[n];
          outf[(size_t)m * NN + n] = outf[(size_t)m * NN + n] +
                                     gate[(size_t)(m >> 11) * THREE_D + n] * v;
        }
      }
    }
  }
}

}  // namespace

extern "C" void kernel_launch(void* const* d_in, const int* in_sizes, int n_in,
                              void* d_out, int out_size, void* d_ws, size_t ws_size,
                              hipStream_t stream) {
  const float* x       = (const float*)d_in[0];
  const float* t       = (const float*)d_in[1];
  const int*   mask    = (const int*)d_in[2];
  const float* ada_w   = (const float*)d_in[3];
  const float* ada_b   = (const float*)d_in[4];
  const float* ssm_w1  = (const float*)d_in[5];
  const float* ssm_b1  = (const float*)d_in[6];
  const float* ssm_w2  = (const float*)d_in[7];
  const float* ssm_b2  = (const float*)d_in[8];
  const float* bwd_w1  = (const float*)d_in[9];
  const float* bwd_b1  = (const float*)d_in[10];
  const float* bwd_w2  = (const float*)d_in[11];
  const float* bwd_b2  = (const float*)d_in[12];
  const float* ffada_w = (const float*)d_in[13];
  const float* ffada_b = (const float*)d_in[14];
  const float* ff_w1   = (const float*)d_in[15];
  const float* ff_b1   = (const float*)d_in[16];
  const float* ff_w2   = (const float*)d_in[17];
  const float* ff_b2   = (const float*)d_in[18];
  float* out = (float*)d_out;

  char* ws = (char*)d_ws;
  u16* normb = (u16*)ws;                                        // 16384*1024 bf16 (32 MB)
  u16* Hb    = (u16*)(ws + (size_t)M_ * D_ * 2);                // 16384*2048 bf16 (64 MB)
  u16* w1t   = (u16*)(ws + (size_t)M_ * D_ * 2 + (size_t)M_ * 2 * D_ * 2);
  u16* w2t   = w1t + (size_t)2 * D_ * D_;
  u16* fw1t  = w2t + (size_t)2 * D_ * D_;
  u16* fw2t  = fw1t + (size_t)2 * D_ * D_;
  float* emb   = (float*)(fw2t + (size_t)2 * D_ * D_);          // [8][3072]
  float* ffada = emb + B_ * THREE_D;                            // [8][3072]
  float* part0 = (float*)Hb;                                    // [4][8][3072]
  float* part1 = part0 + 4 * B_ * THREE_D;

  dim3 tb(32, 8);
  packT<<<dim3(64, 32), tb, 0, stream>>>(ssm_w1, bwd_w1, w1t, D_, 2 * D_, 1);
  packT<<<dim3(32, 64), tb, 0, stream>>>(ssm_w2, bwd_w2, w2t, 2 * D_, D_, 2);
  packT<<<dim3(64, 32), tb, 0, stream>>>(ff_w1, nullptr, fw1t, D_, 2 * D_, 0);
  packT<<<dim3(32, 64), tb, 0, stream>>>(ff_w2, nullptr, fw2t, 2 * D_, D_, 0);

  ada_part<<<dim3(12, 4), 256, 0, stream>>>(t, ada_w, part0);
  ada_part<<<dim3(12, 4), 256, 0, stream>>>(t, ffada_w, part1);
  ada_reduce<<<dim3(12, 8), 256, 0, stream>>>(part0, ada_b, emb);
  ada_reduce<<<dim3(12, 8), 256, 0, stream>>>(part1, ffada_b, ffada);

  ln_mod<<<M_, 256, 0, stream>>>(x, emb, normb);

  // H = gelu(norm @ W1cat + b1cat)                [16384 x 2048]
  gemm_bt<0, 2048, 1024><<<2048, 256, 0, stream>>>(normb, w1t,
                                                   ssm_b1, bwd_b1, nullptr, nullptr, nullptr,
                                                   nullptr, Hb);
  // x_mid = x + mask*gate_msa*(H @ W2cat + b2sum) -> d_out
  gemm_bt<2, 1024, 2048><<<1024, 256, 0, stream>>>(Hb, w2t,
                                                   ssm_b2, bwd_b2, x, mask, emb + 2 * D_,
                                                   out, nullptr);
  ln_mod<<<M_, 256, 0, stream>>>(out, ffada, normb);

  // H = gelu(ff_norm @ ff_w1 + ff_b1)             [16384 x 2048]
  gemm_bt<1, 2048, 1024><<<2048, 256, 0, stream>>>(normb, fw1t,
                                                   ff_b1, ff_b1 + D_, nullptr, nullptr, nullptr,
                                                   nullptr, Hb);
  // out = x_mid + gate_mlp*(H @ ff_w2 + ff_b2)    (in-place on d_out)
  gemm_bt<3, 1024, 2048><<<1024, 256, 0, stream>>>(Hb, fw2t,
                                                   ff_b2, nullptr, nullptr, nullptr, ffada + 2 * D_,
                                                   out, nullptr);
}

// Round 16
// 439.367 us; speedup vs baseline: 2.6667x; 1.1094x over previous
//
#include <hip/hip_runtime.h>
#include <hip/hip_bf16.h>

namespace {

constexpr int D_      = 1024;
constexpr int THREE_D = 3072;
constexpr int B_      = 8;
constexpr int M_      = 16384;   // B*L tokens

typedef unsigned short u16;
typedef __attribute__((ext_vector_type(8))) short bf16x8;
typedef __attribute__((ext_vector_type(4))) float f32x4;

__device__ __forceinline__ u16 f2bf(float f) {
  unsigned u = __float_as_uint(f);
  u += 0x7fffu + ((u >> 16) & 1u);   // round-to-nearest-even
  return (u16)(u >> 16);
}

// tanh-form gelu via native v_exp_f32; |err| <= ~3e-3 vs erf-gelu.
__device__ __forceinline__ float gelu_fast(float x) {
  float u = 0.7978845608028654f * (x + 0.044715f * x * x * x);
  float e = __expf(2.0f * u);
  float th = 1.0f - 2.0f * __builtin_amdgcn_rcpf(e + 1.0f);
  return 0.5f * x * (1.0f + th);
}

// direct global->LDS 16B async copy. LDS dest is wave-uniform base + lane*16.
typedef __attribute__((address_space(3))) unsigned int   lds_uint;
typedef const __attribute__((address_space(1))) unsigned int gl_uint;
__device__ __forceinline__ void gload16(const void* g, void* l) {
  __builtin_amdgcn_global_load_lds((gl_uint*)g, (lds_uint*)l, 16, 0, 0);
}

// inline-asm ds_read_b128: opaque to the compiler's waitcnt pass. Plain C++
// LDS reads after global_load_lds issues receive a compiler-inserted
// s_waitcnt vmcnt(0) (gload_lds writes LDS -> alias safety). That implicit
// drain sat before EVERY phase's reads in rounds 8-12, nullifying all
// counted-vmcnt schedules (r15 confirmed the mechanism: asm reads +6% even
// at full-tile distance). We supply lgkmcnt(0)+sched_barrier(0) ourselves
// (rule #18).
typedef __attribute__((address_space(3))) const u16 lds_cu16;
__device__ __forceinline__ bf16x8 ds_read128(const u16* p) {
  bf16x8 r;
  asm volatile("ds_read_b128 %0, %1" : "=v"(r) : "v"((lds_cu16*)p));
  return r;
}

#define BAR() asm volatile("s_barrier" ::: "memory")

// ---------- weight transpose + f32->bf16 pack ----------
__global__ void packT(const float* __restrict__ s0, const float* __restrict__ s1,
                      u16* __restrict__ dst, int K, int N, int mode) {
  __shared__ float tile[32][33];
  int n0 = blockIdx.x * 32, k0 = blockIdx.y * 32;
  int tx = threadIdx.x, ty = threadIdx.y;
  for (int i = ty; i < 32; i += 8) {
    int k = k0 + i, n = n0 + tx;
    float v;
    if (mode == 1)      { int h = N >> 1; v = (n < h) ? s0[(size_t)k * h + n] : s1[(size_t)k * h + (n - h)]; }
    else if (mode == 2) { int h = K >> 1; v = (k < h) ? s0[(size_t)k * N + n] : s1[(size_t)(k - h) * N + n]; }
    else                v = s0[(size_t)k * N + n];
    tile[i][tx] = v;
  }
  __syncthreads();
  for (int i = ty; i < 32; i += 8) {
    int n = n0 + i, k = k0 + tx;
    dst[(size_t)n * K + k] = f2bf(tile[tx][i]);
  }
}

// ---------- ada embedding, K-split ----------
__global__ __launch_bounds__(256) void ada_part(const float* __restrict__ t,
                                                const float* __restrict__ W,
                                                float* __restrict__ part) {
  __shared__ float s[B_ * 256];
  const int jb = blockIdx.x, kc = blockIdx.y;
  const int tid = threadIdx.x;
  const int k0 = kc * 256;
  for (int idx = tid; idx < B_ * 256; idx += 256) {
    float v = t[((idx >> 8) << 10) + k0 + (idx & 255)];
    s[idx] = v / (1.0f + expf(-v));
  }
  __syncthreads();
  const int j = jb * 256 + tid;
  float acc[B_];
#pragma unroll
  for (int b = 0; b < B_; ++b) acc[b] = 0.f;
  for (int k = 0; k < 256; ++k) {
    const float w = W[(size_t)(k0 + k) * THREE_D + j];
#pragma unroll
    for (int b = 0; b < B_; ++b) acc[b] = fmaf(s[(b << 8) + k], w, acc[b]);
  }
#pragma unroll
  for (int b = 0; b < B_; ++b)
    part[((size_t)kc * B_ + b) * THREE_D + j] = acc[b];
}

__global__ __launch_bounds__(256) void ada_reduce(const float* __restrict__ part,
                                                  const float* __restrict__ bias,
                                                  float* __restrict__ out) {
  const int j = blockIdx.x * 256 + threadIdx.x;
  const int b = blockIdx.y;
  float v = bias[j];
#pragma unroll
  for (int kc = 0; kc < 4; ++kc) v += part[((size_t)kc * B_ + b) * THREE_D + j];
  out[(size_t)b * THREE_D + j] = v;
}

// ---------- LayerNorm + adaLN modulate -> bf16 ----------
__global__ __launch_bounds__(256) void ln_mod(const float* __restrict__ in,
                                              const float* __restrict__ modv,
                                              u16* __restrict__ out) {
  const int row = blockIdx.x;
  const int b = row >> 11;  // L = 2048
  const int tid = threadIdx.x;
  const float4 v = *(const float4*)(in + (size_t)row * D_ + tid * 4);
  float s = v.x + v.y + v.z + v.w;
  float q = v.x * v.x + v.y * v.y + v.z * v.z + v.w * v.w;
#pragma unroll
  for (int off = 32; off > 0; off >>= 1) {
    s += __shfl_down(s, off);
    q += __shfl_down(q, off);
  }
  __shared__ float red[8];
  const int wave = tid >> 6, lane = tid & 63;
  if (lane == 0) { red[wave] = s; red[4 + wave] = q; }
  __syncthreads();
  float ts = red[0] + red[1] + red[2] + red[3];
  float tq = red[4] + red[5] + red[6] + red[7];
  const float mu = ts * (1.0f / D_);
  const float var = tq * (1.0f / D_) - mu * mu;
  const float rstd = rsqrtf(var + 1e-6f);
  const float4 sh = *(const float4*)(modv + (size_t)b * THREE_D + tid * 4);
  const float4 sc = *(const float4*)(modv + (size_t)b * THREE_D + D_ + tid * 4);
  float o0 = (v.x - mu) * rstd * (1.0f + sc.x) + sh.x;
  float o1 = (v.y - mu) * rstd * (1.0f + sc.y) + sh.y;
  float o2 = (v.z - mu) * rstd * (1.0f + sc.z) + sh.z;
  float o3 = (v.w - mu) * rstd * (1.0f + sc.w) + sh.w;
  uint2 pk;
  pk.x = (unsigned)f2bf(o0) | ((unsigned)f2bf(o1) << 16);
  pk.y = (unsigned)f2bf(o2) | ((unsigned)f2bf(o3) << 16);
  *(uint2*)(out + (size_t)row * D_ + tid * 4) = pk;
}

// ---------- bf16 MFMA GEMM, 256x256, 8 waves, 4-phase counted + asm reads --
// Round-16 = round-12's verified ledger with the reads de-instrumented.
// Ledger (per-wave FIFO; invariant at tile start: outstanding = M_t={A1,A3}):
//   ph0: asm-read af0/bf0 (L_t, published by t-1 ph3) | issue B'x4 -> 6
//        | lgkm0+schedbar | 16 MFMA
//   ph1: asm-read af1/bf1 | issue A0',A2' -> 8 | vmcnt(6): M_t lands | BAR
//        | lgkm0+schedbar | 16 MFMA
//   ph2: asm-read af0(qm1) (M_t) | issue A1',A3' -> 8 | lgkm0+schedbar | 16 MFMA
//   ph3: asm-read af1(qm1) | vmcnt(2): L_{t+1} lands, M_{t+1} flying | BAR
//        (publish + WAR fence) | lgkm0+schedbar | 16 MFMA
constexpr int BM = 256, BN = 256, BK = 64;

template <int EPI, int NN, int KK>
__global__ __launch_bounds__(512, 2)
void gemm_bt(const u16* __restrict__ A, const u16* __restrict__ Bt,
             const float* __restrict__ b0, const float* __restrict__ b1,
             const float* __restrict__ xres, const int* __restrict__ mask,
             const float* __restrict__ gate,
             float* __restrict__ outf, u16* __restrict__ outh) {
  __shared__ u16 As[2][BM * BK];
  __shared__ u16 Bs[2][BN * BK];
  const int tid = threadIdx.x;
  const int wave = tid >> 6, lane = tid & 63;
  const int wr = wave >> 2, wc = wave & 3;
  const int l15 = lane & 15, l4 = lane >> 4;

  constexpr int LGX = (NN == 2048) ? 3 : 2;
  const int nwg = gridDim.x;
  const int flat = blockIdx.x;
  const int swz = (flat & 7) * (nwg >> 3) + (flat >> 3);
  const int bx = swz & ((1 << LGX) - 1), by = swz >> LGX;
  const int m0 = by * BM, n0 = bx * BN;

  // staging: quarter q rows [q*64,q*64+64); wave w covers rows q*64+w*8..+8.
  const int sg = (lane & 7) ^ (lane >> 3);       // inverse-XOR global slot
  const int srow = wave * 8 + (lane >> 3);
  const u16* ga = A  + (size_t)(m0 + srow) * KK + sg * 8;
  const u16* gb = Bt + (size_t)(n0 + srow) * KK + sg * 8;
  const int ldq = wave * 8 * BK;                 // wave-uniform LDS sub-offset

  // loop-invariant swizzled read offsets
  const int swz0 = ((l4 ^ (l15 & 7)) << 3);
  const int swz1 = (((4 + l4) ^ (l15 & 7)) << 3);
  const int arow = (wr * 128 + l15) * BK;
  const int brow = (wc * 64 + l15) * BK;

  f32x4 acc[8][4];
#pragma unroll
  for (int i = 0; i < 8; ++i)
#pragma unroll
    for (int j = 0; j < 4; ++j) acc[i][j] = (f32x4){0.f, 0.f, 0.f, 0.f};

  constexpr int NT = KK / BK;

#define STG_A(q, dst, gp) gload16((gp) + (size_t)((q) * 64) * KK, (dst) + ((q) * 64) * BK + ldq)
#define STG_B(q, dst, gp) gload16((gp) + (size_t)((q) * 64) * KK, (dst) + ((q) * 64) * BK + ldq)
#define LGKM0() do { asm volatile("s_waitcnt lgkmcnt(0)" ::: "memory"); \
                     __builtin_amdgcn_sched_barrier(0); } while (0)

  // prologue: stage tile 0 (L0 then M0), confirm L0, leave M0 flying
  STG_B(0, Bs[0], gb); STG_B(1, Bs[0], gb); STG_B(2, Bs[0], gb); STG_B(3, Bs[0], gb);
  STG_A(0, As[0], ga); STG_A(2, As[0], ga);
  STG_A(1, As[0], ga); STG_A(3, As[0], ga);
  asm volatile("s_waitcnt vmcnt(2)" ::: "memory");
  BAR();

  const u16* gan = ga + BK;    // points at tile t+1
  const u16* gbn = gb + BK;

  bf16x8 af0[4], af1[4], bf0[4], bf1[4];
  for (int t = 0; t < NT; ++t) {
    const u16* as = As[t & 1];
    const u16* bs = Bs[t & 1];
    u16* An = As[(t + 1) & 1];
    u16* Bn = Bs[(t + 1) & 1];
    const bool pre = (t + 1 < NT);

    // ---- ph0: qm0 ks0 (no barrier; L_t published by t-1 ph3) ----
#pragma unroll
    for (int i = 0; i < 4; ++i) af0[i] = ds_read128(as + arow + i * 16 * BK + swz0);
#pragma unroll
    for (int j = 0; j < 4; ++j) bf0[j] = ds_read128(bs + brow + j * 16 * BK + swz0);
    if (pre) { STG_B(0, Bn, gbn); STG_B(1, Bn, gbn); STG_B(2, Bn, gbn); STG_B(3, Bn, gbn); }
    LGKM0();
    __builtin_amdgcn_s_setprio(1);
#pragma unroll
    for (int i = 0; i < 4; ++i)
#pragma unroll
      for (int j = 0; j < 4; ++j)
        acc[i][j] = __builtin_amdgcn_mfma_f32_16x16x32_bf16(af0[i], bf0[j], acc[i][j], 0, 0, 0);
    __builtin_amdgcn_s_setprio(0);

    // ---- ph1: qm0 ks1 ----
#pragma unroll
    for (int i = 0; i < 4; ++i) af1[i] = ds_read128(as + arow + i * 16 * BK + swz1);
#pragma unroll
    for (int j = 0; j < 4; ++j) bf1[j] = ds_read128(bs + brow + j * 16 * BK + swz1);
    if (pre) {
      STG_A(0, An, gan); STG_A(2, An, gan);
      asm volatile("s_waitcnt vmcnt(6)" ::: "memory");   // M_t (A1,A3) landed
    } else {
      asm volatile("s_waitcnt vmcnt(0)" ::: "memory");
    }
    BAR();                                               // publish M_t
    LGKM0();
    __builtin_amdgcn_s_setprio(1);
#pragma unroll
    for (int i = 0; i < 4; ++i)
#pragma unroll
      for (int j = 0; j < 4; ++j)
        acc[i][j] = __builtin_amdgcn_mfma_f32_16x16x32_bf16(af1[i], bf1[j], acc[i][j], 0, 0, 0);
    __builtin_amdgcn_s_setprio(0);

    // ---- ph2: qm1 ks0 (A from M_t; B regs reused; no barrier) ----
#pragma unroll
    for (int i = 0; i < 4; ++i) af0[i] = ds_read128(as + arow + (64 + i * 16) * BK + swz0);
    if (pre) { STG_A(1, An, gan); STG_A(3, An, gan); }
    LGKM0();
    __builtin_amdgcn_s_setprio(1);
#pragma unroll
    for (int i = 0; i < 4; ++i)
#pragma unroll
      for (int j = 0; j < 4; ++j)
        acc[4 + i][j] = __builtin_amdgcn_mfma_f32_16x16x32_bf16(af0[i], bf0[j], acc[4 + i][j], 0, 0, 0);
    __builtin_amdgcn_s_setprio(0);

    // ---- ph3: qm1 ks1 ----
#pragma unroll
    for (int i = 0; i < 4; ++i) af1[i] = ds_read128(as + arow + (64 + i * 16) * BK + swz1);
    if (pre) asm volatile("s_waitcnt vmcnt(2)" ::: "memory");  // L_{t+1} lands
    BAR();                                   // publish L_{t+1}; WAR fence
    LGKM0();
    __builtin_amdgcn_s_setprio(1);
#pragma unroll
    for (int i = 0; i < 4; ++i)
#pragma unroll
      for (int j = 0; j < 4; ++j)
        acc[4 + i][j] = __builtin_amdgcn_mfma_f32_16x16x32_bf16(af1[i], bf1[j], acc[4 + i][j], 0, 0, 0);
    __builtin_amdgcn_s_setprio(0);

    gan += BK; gbn += BK;
  }
#undef STG_A
#undef STG_B
#undef LGKM0

#pragma unroll
  for (int i = 0; i < 8; ++i) {
#pragma unroll
    for (int r = 0; r < 4; ++r) {
      const int m = m0 + wr * 128 + i * 16 + l4 * 4 + r;
#pragma unroll
      for (int j = 0; j < 4; ++j) {
        const int n = n0 + wc * 64 + j * 16 + l15;
        float v = acc[i][j][r];
        if constexpr (EPI == 0 || EPI == 1) {
          v += (n < (NN >> 1)) ? b0[n] : b1[n - (NN >> 1)];
          outh[(size_t)m * NN + n] = f2bf(gelu_fast(v));
        } else if constexpr (EPI == 2) {
          v += b0[n] + b1[n];
          float res = xres[(size_t)m * NN + n];
          if (mask[m] != 0) res += gate[(size_t)(m >> 11) * THREE_D + n] * v;
          outf[(size_t)m * NN + n] = res;
        } else {
          v += b0[n];
          outf[(size_t)m * NN + n] = outf[(size_t)m * NN + n] +
                                     gate[(size_t)(m >> 11) * THREE_D + n] * v;
        }
      }
    }
  }
}

}  // namespace

extern "C" void kernel_launch(void* const* d_in, const int* in_sizes, int n_in,
                              void* d_out, int out_size, void* d_ws, size_t ws_size,
                              hipStream_t stream) {
  const float* x       = (const float*)d_in[0];
  const float* t       = (const float*)d_in[1];
  const int*   mask    = (const int*)d_in[2];
  const float* ada_w   = (const float*)d_in[3];
  const float* ada_b   = (const float*)d_in[4];
  const float* ssm_w1  = (const float*)d_in[5];
  const float* ssm_b1  = (const float*)d_in[6];
  const float* ssm_w2  = (const float*)d_in[7];
  const float* ssm_b2  = (const float*)d_in[8];
  const float* bwd_w1  = (const float*)d_in[9];
  const float* bwd_b1  = (const float*)d_in[10];
  const float* bwd_w2  = (const float*)d_in[11];
  const float* bwd_b2  = (const float*)d_in[12];
  const float* ffada_w = (const float*)d_in[13];
  const float* ffada_b = (const float*)d_in[14];
  const float* ff_w1   = (const float*)d_in[15];
  const float* ff_b1   = (const float*)d_in[16];
  const float* ff_w2   = (const float*)d_in[17];
  const float* ff_b2   = (const float*)d_in[18];
  float* out = (float*)d_out;

  char* ws = (char*)d_ws;
  u16* normb = (u16*)ws;                                        // 16384*1024 bf16 (32 MB)
  u16* Hb    = (u16*)(ws + (size_t)M_ * D_ * 2);                // 16384*2048 bf16 (64 MB)
  u16* w1t   = (u16*)(ws + (size_t)M_ * D_ * 2 + (size_t)M_ * 2 * D_ * 2);
  u16* w2t   = w1t + (size_t)2 * D_ * D_;
  u16* fw1t  = w2t + (size_t)2 * D_ * D_;
  u16* fw2t  = fw1t + (size_t)2 * D_ * D_;
  float* emb   = (float*)(fw2t + (size_t)2 * D_ * D_);          // [8][3072]
  float* ffada = emb + B_ * THREE_D;                            // [8][3072]
  float* part0 = (float*)Hb;                                    // [4][8][3072]
  float* part1 = part0 + 4 * B_ * THREE_D;

  dim3 tb(32, 8);
  packT<<<dim3(64, 32), tb, 0, stream>>>(ssm_w1, bwd_w1, w1t, D_, 2 * D_, 1);
  packT<<<dim3(32, 64), tb, 0, stream>>>(ssm_w2, bwd_w2, w2t, 2 * D_, D_, 2);
  packT<<<dim3(64, 32), tb, 0, stream>>>(ff_w1, nullptr, fw1t, D_, 2 * D_, 0);
  packT<<<dim3(32, 64), tb, 0, stream>>>(ff_w2, nullptr, fw2t, 2 * D_, D_, 0);

  ada_part<<<dim3(12, 4), 256, 0, stream>>>(t, ada_w, part0);
  ada_part<<<dim3(12, 4), 256, 0, stream>>>(t, ffada_w, part1);
  ada_reduce<<<dim3(12, 8), 256, 0, stream>>>(part0, ada_b, emb);
  ada_reduce<<<dim3(12, 8), 256, 0, stream>>>(part1, ffada_b, ffada);

  ln_mod<<<M_, 256, 0, stream>>>(x, emb, normb);

  // H = gelu(norm @ W1cat + b1cat)                [16384 x 2048]
  gemm_bt<0, 2048, 1024><<<512, 512, 0, stream>>>(normb, w1t,
                                                  ssm_b1, bwd_b1, nullptr, nullptr, nullptr,
                                                  nullptr, Hb);
  // x_mid = x + mask*gate_msa*(H @ W2cat + b2sum) -> d_out
  gemm_bt<2, 1024, 2048><<<256, 512, 0, stream>>>(Hb, w2t,
                                                  ssm_b2, bwd_b2, x, mask, emb + 2 * D_,
                                                  out, nullptr);
  ln_mod<<<M_, 256, 0, stream>>>(out, ffada, normb);

  // H = gelu(ff_norm @ ff_w1 + ff_b1)             [16384 x 2048]
  gemm_bt<1, 2048, 1024><<<512, 512, 0, stream>>>(normb, fw1t,
                                                  ff_b1, ff_b1 + D_, nullptr, nullptr, nullptr,
                                                  nullptr, Hb);
  // out = x_mid + gate_mlp*(H @ ff_w2 + ff_b2)    (in-place on d_out)
  gemm_bt<3, 1024, 2048><<<256, 512, 0, stream>>>(Hb, fw2t,
                                                  ff_b2, nullptr, nullptr, nullptr, ffada + 2 * D_,
                                                  out, nullptr);
}